// Round 12
// baseline (221.999 us; speedup 1.0000x reference)
//
#include <hip/hip_runtime.h>
#include <math.h>

#define NB    16        // batch
#define NC    25        // channels
#define HW    65536     // 256*256
#define CHW   (NC * HW)
#define EPSF  1e-8f
#define TPB   256       // 4 waves, 1 px per thread
#define PXB   256       // pixels per block
#define NBLK  (NB * (HW / PXB))   // 4096 blocks
#define NSTR  64        // accumulator stripes (parallel atomic chains)
#define SACC  64        // floats per stripe

__device__ __forceinline__ float wave_reduce(float v) {
#pragma unroll
    for (int o = 32; o > 0; o >>= 1) v += __shfl_down(v, o, 64);
    return v;
}

// R19: value-fence experiment. R18 post-mortem: VGPR=32 with 50 volatile-asm
// load outputs is only possible if the CONSUMES were interleaved between the
// loads before regalloc (no spill traffic -> not spilled). Mechanism: the
// BCE/argmax arithmetic is PURE; IR-level motion may hoist pure ops above
// sched_barrier/waitcnt (they don't touch memory) and place each use right
// after its def -> initial MIR is load->use->load->use, SIInsertWaitcnts
// adds a vmcnt before every use -> serialized. Ninth kernel at ~75us,
// warm(L3)==cold(HBM) throughout.
// Fix: after the 50 loads + one s_waitcnt vmcnt(0), pass EVERY value through
// an empty volatile asm with "+v" (zero instructions): volatile<->volatile
// order pins each fence after the waitcnt; the fence consumes the load
// result and REDEFINES it, and pure code can only read the redefinition --
// which does not exist before the fence. No legal transform can shorten the
// load live ranges now: the allocator must hold ~50 payload VGPRs and the
// emitted code must issue 50 loads back-to-back.
// Discriminator: H1 (software serialization was the wall) -> 30-45us.
// H2 (per-CU outstanding-line cap ~64 lines @ ~375ns = 10.9GB/s/CU, which
// reproduces 75us exactly) -> VGPR rises but dur stays ~75us; next step
// would be wave-contiguous streams + LDS transpose.
__global__ __launch_bounds__(TPB) void yolo_main(const float* __restrict__ outputs,
                                                 const float* __restrict__ labels,
                                                 float* __restrict__ acc) {
    const int wv   = threadIdx.x >> 6;
    const int lane = threadIdx.x & 63;
    const int b    = blockIdx.x >> 8;                      // image
    const int px   = ((blockIdx.x & 255) << 8) + threadIdx.x;

    // byte offset of this thread's channel-0 element (same for both tensors)
    unsigned voff = (unsigned)(((size_t)b * CHW + px) * sizeof(float));

    // ---- 50 loads issued back-to-back (volatile asm, fixed mutual order)
    float o[NC], l[NC];
#pragma unroll
    for (int c = 0; c < NC; ++c) {
        asm volatile("global_load_dword %0, %1, %2"
                     : "=v"(o[c]) : "v"(voff), "s"(outputs));
        asm volatile("global_load_dword %0, %1, %2"
                     : "=v"(l[c]) : "v"(voff), "s"(labels));
        voff += HW * sizeof(float);          // next channel plane (+256KB)
    }
    asm volatile("s_waitcnt vmcnt(0)");
    // value fences: zero-instruction volatile asms, ordered AFTER the waitcnt,
    // that consume and redefine every loaded value. Pure code can only see
    // the redefinitions -> load live ranges forcibly span all 50 issues.
#pragma unroll
    for (int c = 0; c < NC; ++c) {
        asm volatile("" : "+v"(o[c]));
        asm volatile("" : "+v"(l[c]));
    }

    // ---- channel 0: BCE + F1 counters
    const float xv = o[0], yv = l[0];
    float xc = fminf(fmaxf(xv,        EPSF), 1.0f - EPSF);
    float x1 = fminf(fmaxf(1.0f - xv, EPSF), 1.0f - EPSF);
    float obj = -yv * (1.0f - xc) * __logf(xc)
                - (1.0f - yv) * (1.0f - x1) * __logf(x1);
    const float p  = (xv > 0.5f) ? 1.f : 0.f;
    const float yt = (yv > 0.5f) ? 1.f : 0.f;
    float tp = p * yt;
    float fp = p * (1.f - yt);
    float fn = (1.f - p) * yt;

    // ---- channels 1..4: size / offset L1 (weighted by y)
    float szs  = yv * (fabsf(o[1] - l[1]) + fabsf(o[2] - l[2]));
    float offs = yv * (fabsf(o[3] - l[3]) + fabsf(o[4] - l[4]));

    // ---- channels 5..24: argmax(labels) carrying outputs
    // ascending c + strict '>' = argmax first-index tie-break
    float vmax = -1.0f, vout = 0.0f;
#pragma unroll
    for (int c = 5; c < NC; ++c) {
        if (l[c] > vmax) { vmax = l[c]; vout = o[c]; }
    }
    float cls = yv * (-vout);

    // ---- block reduction: 7 values
    obj  = wave_reduce(obj);
    szs  = wave_reduce(szs);
    offs = wave_reduce(offs);
    cls  = wave_reduce(cls);
    tp   = wave_reduce(tp);
    fp   = wave_reduce(fp);
    fn   = wave_reduce(fn);

    __shared__ float sm[TPB / 64][7];
    if (lane == 0) {
        sm[wv][0] = obj;  sm[wv][1] = szs; sm[wv][2] = offs;
        sm[wv][3] = cls;  sm[wv][4] = tp;  sm[wv][5] = fp;  sm[wv][6] = fn;
    }
    __syncthreads();
    if (threadIdx.x < 7) {
        float s = 0.f;
#pragma unroll
        for (int w = 0; w < TPB / 64; ++w) s += sm[w][threadIdx.x];
        // striped accumulators: 64 parallel short atomic chains (R13 win)
        float* st = acc + (size_t)(blockIdx.x & (NSTR - 1)) * SACC;
        if (threadIdx.x < 4) atomicAdd(st + threadIdx.x, s);
        else                 atomicAdd(st + 4 + 3 * b + (threadIdx.x - 4), s);
    }
}

__global__ void yolo_fin(const float* __restrict__ acc, float* __restrict__ out) {
    const int t = threadIdx.x;                // 64 threads, 1 wave
    __shared__ float fin[52];
    if (t < 52) {
        float s = 0.f;
#pragma unroll
        for (int st = 0; st < NSTR; ++st) s += acc[st * SACC + t];
        fin[t] = s;
    }
    __syncthreads();
    if (t == 0) {
        float objT = fin[0];
        float szT  = 0.1f * fin[1];
        float offT = 0.1f * fin[2];
        float clsT = fin[3];
        float f1 = 0.f;
        for (int bb = 0; bb < NB; ++bb) {
            float tpv = fin[4 + 3 * bb], fpv = fin[5 + 3 * bb], fnv = fin[6 + 3 * bb];
            float den = 2.f * tpv + fpv + fnv;
            f1 += (den > 0.f) ? (2.f * tpv) / fmaxf(den, 1.f) : 0.f;
        }
        f1 *= (1.0f / NB);
        out[0] = objT + szT + offT + clsT;
        out[1] = f1;
        out[2] = objT;
        out[3] = szT;
        out[4] = offT;
        out[5] = clsT;
    }
}

extern "C" void kernel_launch(void* const* d_in, const int* in_sizes, int n_in,
                              void* d_out, int out_size, void* d_ws, size_t ws_size,
                              hipStream_t stream) {
    const float* outputs = (const float*)d_in[0];
    const float* labels  = (const float*)d_in[1];
    float* acc = (float*)d_ws;   // 64 stripes x 64 floats = 16 KB

    hipMemsetAsync(acc, 0, NSTR * SACC * sizeof(float), stream);
    yolo_main<<<NBLK, TPB, 0, stream>>>(outputs, labels, acc);
    yolo_fin<<<1, 64, 0, stream>>>(acc, (float*)d_out);
}